// Round 11
// baseline (223.414 us; speedup 1.0000x reference)
//
#include <hip/hip_runtime.h>
#include <hip/hip_fp16.h>
#include <cstdint>

#define CDIM 40
#define FDIM 128
#define BIN_SHIFT 7      // 128 nodes per bin
#define BIN_SZ (1 << BIN_SHIFT)
#define CHUNK 2048       // edges per binning chunk
#define STAGE_CAP 4096   // LDS-staged csr ints per bin (16KB)

typedef _Float16 f16x8 __attribute__((ext_vector_type(8)));
typedef float f32x4 __attribute__((ext_vector_type(4)));

static __device__ __forceinline__ long long load_idx(const void* p, int is64, long long i) {
    if (is64) return ((const long long*)p)[i];
    return (long long)((const int*)p)[i];
}

static __device__ __forceinline__ unsigned packh2(float a, float b) {
    __half2 h;
    h.x = __float2half(a);
    h.y = __float2half(b);
    return *(unsigned*)&h;
}

// add 8 fp16 values (one uint4) into acc[0..8)
static __device__ __forceinline__ void addv(float* acc, uint4 v) {
    const __half2* h = (const __half2*)&v;
#pragma unroll
    for (int k = 0; k < 4; ++k) {
        float2 f = __half22float2(h[k]);
        acc[2 * k]     += f.x;
        acc[2 * k + 1] += f.y;
    }
}

static __device__ __forceinline__ f16x8 cvt8(float4 a, float4 b) {
    f16x8 r;
    r[0] = (_Float16)a.x; r[1] = (_Float16)a.y; r[2] = (_Float16)a.z; r[3] = (_Float16)a.w;
    r[4] = (_Float16)b.x; r[5] = (_Float16)b.y; r[6] = (_Float16)b.z; r[7] = (_Float16)b.w;
    return r;
}

// Init capacity cursors (tiny).
__global__ void k_init(int* cursor, int nb, int capRec) {
    int i = blockIdx.x * blockDim.x + threadIdx.x;
    if (i < nb) cursor[i] = i * capRec;
}

// Binning scatter into capacity-laid-out bins. Inline int64-vs-int32 detect
// (int64 LE values < 2^31 have all odd 32-bit words zero; impossible over
// ~2048 genuine int32 ids). Stage chunk in LDS, reserve per-bin ranges via
// global cursors, scatter 4B packed {dlocal:7 | src:17}. N <= 131072, nb <= 1024.
__global__ __launch_bounds__(256) void kA3(const void* ei, long long E,
                                           int nb, int* __restrict__ cursor,
                                           unsigned* __restrict__ binned) {
    __shared__ unsigned lval[CHUNK];
    __shared__ unsigned short lbin[CHUNK];
    __shared__ int lcnt[1024];
    __shared__ int lbase[1024];
    __shared__ int lflag;
    int tid = threadIdx.x;
    if (tid == 0) lflag = 1;
    for (int i = tid; i < nb; i += 256) lcnt[i] = 0;
    __syncthreads();
    {
        const unsigned* w = (const unsigned*)ei;
        int nscan = (int)((2 * E < 4096) ? (2 * E) : 4096);
        for (int k = 1 + 2 * tid; k < nscan; k += 512)
            if (w[k] != 0u) lflag = 0;
    }
    __syncthreads();
    int is64 = lflag;
    long long base = (long long)blockIdx.x * CHUNK;
    int nk = (int)min((long long)CHUNK, E - base);
    for (int k = tid; k < nk; k += 256) {
        long long e = base + k;
        int s = (int)load_idx(ei, is64, e);
        int d = (int)load_idx(ei, is64, E + e);
        int bin = d >> BIN_SHIFT;
        lval[k] = (unsigned)s | ((unsigned)(d & (BIN_SZ - 1)) << 17);
        lbin[k] = (unsigned short)bin;
        atomicAdd(&lcnt[bin], 1);
    }
    __syncthreads();
    for (int i = tid; i < nb; i += 256) {
        int c = lcnt[i];
        lbase[i] = c ? atomicAdd(&cursor[i], c) : 0;
        lcnt[i] = 0;
    }
    __syncthreads();
    for (int k = tid; k < nk; k += 256) {
        int bin = lbin[k];
        int loc = atomicAdd(&lcnt[bin], 1);
        binned[lbase[bin] + loc] = lval[k];
    }
}

// Pass B: one block (256 thr) per bin (128 nodes). Per-node degree, dinv,
// packed permuted meta {rowp, node|deg<<17}, and the CSR segment: each node's
// list 4-aligned, padded with sentinel src=N (zero row). LDS build, int4 out.
__global__ __launch_bounds__(256) void kB(const unsigned* __restrict__ binned,
                                          const int* __restrict__ cursor,
                                          int capRec, int capC,
                                          int2* __restrict__ meta,
                                          float* __restrict__ dinv,
                                          int* __restrict__ cursorG,
                                          int* __restrict__ csr, int N) {
    __shared__ int lcnt[BIN_SZ];
    __shared__ int lexcl[BIN_SZ];
    __shared__ int ls[256];
    __shared__ int dh[64];
    __shared__ int tot;
    __shared__ int stage[STAGE_CAP];
    int b = blockIdx.x, tid = threadIdx.x;
    int node0 = b << BIN_SHIFT;
    int nn = min(BIN_SZ, N - node0);
    int recBase = b * capRec;
    int csrBase = b * capC;
    int nedges = cursor[b] - recBase;

    if (tid < BIN_SZ) lcnt[tid] = 0;
    if (tid < 64) dh[tid] = 0;
    __syncthreads();
    for (int t = tid; t < nedges; t += 256)
        atomicAdd(&lcnt[(binned[recBase + t] >> 17) & (BIN_SZ - 1)], 1);
    __syncthreads();
    int myc = (tid < BIN_SZ) ? lcnt[tid] : 0;
    int psz = (myc + 3) & ~3;          // padded size (4-aligned)
    ls[tid] = (tid < BIN_SZ) ? psz : 0;
    __syncthreads();
    for (int off = 1; off < 256; off <<= 1) {
        int t = (tid >= off) ? ls[tid - off] : 0;
        __syncthreads();
        ls[tid] += t;
        __syncthreads();
    }
    int ex = ls[tid] - psz;            // 4-aligned start within bin
    if (tid < BIN_SZ) lexcl[tid] = ex;
    if (tid == BIN_SZ - 1) tot = ls[BIN_SZ - 1];
    if (tid < nn) {
        dinv[node0 + tid] = rsqrtf(1.0f + (float)myc);
        atomicAdd(&dh[min(myc, 63)], 1);
    }
    __syncthreads();
    int total = tot;                   // padded edge count of this bin
    // exclusive scan of 64 degree buckets
    int dv = (tid < 64) ? dh[tid] : 0;
    ls[tid] = dv;
    __syncthreads();
    for (int off = 1; off < 64; off <<= 1) {
        int t = (tid >= off) ? ls[tid - off] : 0;
        __syncthreads();
        ls[tid] += t;
        __syncthreads();
    }
    if (tid < 64) dh[tid] = ls[tid] - dv;
    __syncthreads();
    // degree-sorted permuted meta (ascending degree within bin)
    if (tid < nn) {
        int pos = atomicAdd(&dh[min(myc, 63)], 1);
        int2 mi;
        mi.x = csrBase + ex;
        mi.y = (node0 + tid) | (myc << 17);
        meta[node0 + pos] = mi;
    }
    __syncthreads();
    if (tid < BIN_SZ) lcnt[tid] = ex;  // cursors (real-entry region start)
    __syncthreads();
    if (total <= STAGE_CAP) {
        // prefill with sentinel N (covers pad slots)
        for (int t = tid; t < total; t += 256) stage[t] = N;
        __syncthreads();
        for (int t = tid; t < nedges; t += 256) {
            unsigned v = binned[recBase + t];
            int src = (int)(v & 0x1FFFFu);
            int dl  = (int)((v >> 17) & (BIN_SZ - 1));
            int p = atomicAdd(&lcnt[dl], 1);
            stage[p] = src;
        }
        __syncthreads();
        const int4* sp = (const int4*)stage;
        int4* cp = (int4*)(csr + csrBase);
        for (int t = tid; t < (total >> 2); t += 256) cp[t] = sp[t];
    } else {
        // overflow fallback (never hit for random graphs): global cursors
        if (tid < nn) cursorG[node0 + tid] = csrBase + ex;
        __syncthreads();
        for (int t = tid; t < nedges; t += 256) {
            unsigned v = binned[recBase + t];
            int src = (int)(v & 0x1FFFFu);
            int dl  = (int)((v >> 17) & (BIN_SZ - 1));
            int p = atomicAdd(&cursorG[node0 + dl], 1);
            csr[p] = src;
        }
        if (tid < nn)
            for (int k = myc; k < psz; ++k) csr[csrBase + ex + k] = N;
    }
}

// MFMA gemm: g[i,c] = fp16( dinv[i] * sum_f x[i,f]*W[c,f] ), split-store into
// gA[node][32ch] (64B rows) + gB[node][8ch] (16B rows). Wave = 16 nodes x 48ch
// (3 n-tiles, cols 40..47 zero-padded W). W lives in 12 register B-fragments.
// Also zeroes sentinel row N of gA/gB (pads in csr point at it).
__global__ __launch_bounds__(256) void k_gemm(const float* __restrict__ x,
                                              const float* __restrict__ W,
                                              const float* __restrict__ dinv,
                                              __half* __restrict__ gA,
                                              __half* __restrict__ gB, int N) {
    if (blockIdx.x == 0 && threadIdx.x < 20) {
        if (threadIdx.x < 16) ((unsigned*)(gA + (size_t)N * 32))[threadIdx.x] = 0u;
        else                  ((unsigned*)(gB + (size_t)N * 8))[threadIdx.x - 16] = 0u;
    }
    int wave = threadIdx.x >> 6;
    int lane = threadIdx.x & 63;
    int m = lane & 15;
    int quad = lane >> 4;
    f16x8 bfrag[3][4];
#pragma unroll
    for (int t = 0; t < 3; ++t) {
        int c = t * 16 + m;
#pragma unroll
        for (int q = 0; q < 4; ++q) {
            if (c < CDIM) {
                const float* wp = W + (size_t)c * FDIM + q * 32 + quad * 8;
                float4 w0 = *(const float4*)wp;
                float4 w1 = *(const float4*)(wp + 4);
                bfrag[t][q] = cvt8(w0, w1);
            } else {
                f16x8 z = {0, 0, 0, 0, 0, 0, 0, 0};
                bfrag[t][q] = z;
            }
        }
    }
#pragma unroll
    for (int i = 0; i < 4; ++i) {
        int nodebase = blockIdx.x * 256 + wave * 64 + i * 16;
        if (nodebase >= N) break;
        const float* xp = x + (size_t)(nodebase + m) * FDIM + quad * 8;
        f16x8 afrag[4];
#pragma unroll
        for (int q = 0; q < 4; ++q) {
            float4 x0 = *(const float4*)(xp + q * 32);
            float4 x1 = *(const float4*)(xp + q * 32 + 4);
            afrag[q] = cvt8(x0, x1);
        }
        f32x4 acc0 = {0, 0, 0, 0}, acc1 = {0, 0, 0, 0}, acc2 = {0, 0, 0, 0};
#pragma unroll
        for (int q = 0; q < 4; ++q) {
            acc0 = __builtin_amdgcn_mfma_f32_16x16x32_f16(afrag[q], bfrag[0][q], acc0, 0, 0, 0);
            acc1 = __builtin_amdgcn_mfma_f32_16x16x32_f16(afrag[q], bfrag[1][q], acc1, 0, 0, 0);
            acc2 = __builtin_amdgcn_mfma_f32_16x16x32_f16(afrag[q], bfrag[2][q], acc2, 0, 0, 0);
        }
        float4 dvv = *(const float4*)&dinv[nodebase + quad * 4];
        float ds[4] = {dvv.x, dvv.y, dvv.z, dvv.w};
#pragma unroll
        for (int r = 0; r < 4; ++r) {
            int node = nodebase + quad * 4 + r;
            gA[(size_t)node * 32 + m]      = __float2half(acc0[r] * ds[r]);
            gA[(size_t)node * 32 + 16 + m] = __float2half(acc1[r] * ds[r]);
            if (m < 8)
                gB[(size_t)node * 8 + m]   = __float2half(acc2[r] * ds[r]);
        }
    }
}

// One hop in g-space. Thread = (gidx, 8-ch chunk); meta[gidx] (permuted) packs
// {rowp, node|deg<<17}; csr read as int4 (4-aligned padded lists, pads -> zero
// row N). c<4 reads gA (64B rows), c=4 reads gB (L2-resident). dinv recomputed
// from deg. mode 0: write split fp16 (+ zero row N); mode 1: fp32 out + bias.
__global__ __launch_bounds__(256) void k_gather(const int2* __restrict__ meta,
                                                const int* __restrict__ csr,
                                                const __half* __restrict__ gA,
                                                const __half* __restrict__ gB,
                                                const float* __restrict__ b,
                                                __half* __restrict__ goA,
                                                __half* __restrict__ goB,
                                                float* __restrict__ outF,
                                                int N, int mode) {
    unsigned t = blockIdx.x * 256 + threadIdx.x;
    if (mode == 0 && t < 20) {
        if (t < 16) ((unsigned*)(goA + (size_t)N * 32))[t] = 0u;
        else        ((unsigned*)(goB + (size_t)N * 8))[t - 16] = 0u;
    }
    unsigned gidx = t / 5, c = t - gidx * 5;
    if (gidx >= (unsigned)N) return;
    int2 mi = meta[gidx];
    int j = mi.x;
    int node = mi.y & 0x1FFFF;
    int deg = mi.y >> 17;
    int end_pad = j + ((deg + 3) & ~3);
    const uint4* src;
    unsigned stride;
    if (c < 4) { src = (const uint4*)gA + c; stride = 4; }
    else       { src = (const uint4*)gB;     stride = 1; }
    float acc[8];
#pragma unroll
    for (int i = 0; i < 8; ++i) acc[i] = 0.0f;
    addv(acc, src[(size_t)node * stride]);
    for (; j + 8 <= end_pad; j += 8) {
        int4 c0 = *(const int4*)&csr[j];
        int4 c1 = *(const int4*)&csr[j + 4];
        uint4 v0 = src[(size_t)c0.x * stride];
        uint4 v1 = src[(size_t)c0.y * stride];
        uint4 v2 = src[(size_t)c0.z * stride];
        uint4 v3 = src[(size_t)c0.w * stride];
        uint4 v4 = src[(size_t)c1.x * stride];
        uint4 v5 = src[(size_t)c1.y * stride];
        uint4 v6 = src[(size_t)c1.z * stride];
        uint4 v7 = src[(size_t)c1.w * stride];
        addv(acc, v0); addv(acc, v1); addv(acc, v2); addv(acc, v3);
        addv(acc, v4); addv(acc, v5); addv(acc, v6); addv(acc, v7);
    }
    if (j < end_pad) {
        int4 c0 = *(const int4*)&csr[j];
        uint4 v0 = src[(size_t)c0.x * stride];
        uint4 v1 = src[(size_t)c0.y * stride];
        uint4 v2 = src[(size_t)c0.z * stride];
        uint4 v3 = src[(size_t)c0.w * stride];
        addv(acc, v0); addv(acc, v1); addv(acc, v2); addv(acc, v3);
    }
    float d = rsqrtf(1.0f + (float)deg);
    if (mode == 0) {
        float s = d * d;
        uint4 o;
        unsigned* w = (unsigned*)&o;
#pragma unroll
        for (int k = 0; k < 4; ++k)
            w[k] = packh2(acc[2 * k] * s, acc[2 * k + 1] * s);
        if (c < 4) ((uint4*)goA)[(size_t)node * 4 + c] = o;
        else       ((uint4*)goB)[node] = o;
    } else {
        const float4* b4 = (const float4*)b + 2 * c;
        float4 bv0 = b4[0], bv1 = b4[1];
        float4 o0, o1;
        o0.x = acc[0] * d + bv0.x; o0.y = acc[1] * d + bv0.y;
        o0.z = acc[2] * d + bv0.z; o0.w = acc[3] * d + bv0.w;
        o1.x = acc[4] * d + bv1.x; o1.y = acc[5] * d + bv1.y;
        o1.z = acc[6] * d + bv1.z; o1.w = acc[7] * d + bv1.w;
        float4* op = (float4*)outF + (size_t)node * 10 + 2 * c;
        op[0] = o0;
        op[1] = o1;
    }
}

static inline size_t align256(size_t v) { return (v + 255) & ~(size_t)255; }

extern "C" void kernel_launch(void* const* d_in, const int* in_sizes, int n_in,
                              void* d_out, int out_size, void* d_ws, size_t ws_size,
                              hipStream_t stream) {
    const float* x  = (const float*)d_in[0];
    const void*  ei = d_in[1];
    const float* W  = (const float*)d_in[2];
    const float* b  = (const float*)d_in[3];
    float* out = (float*)d_out;

    const int N = in_sizes[0] / FDIM;                 // 100000
    const long long E = (long long)in_sizes[1] / 2;   // 1600000

    const int nb     = (N + BIN_SZ - 1) >> BIN_SHIFT;        // 782 bins
    const int nchunk = (int)((E + CHUNK - 1) / CHUNK);       // 782 chunks
    int capRec = (int)(E / nb) + 1024;                       // record capacity (~22 sigma)
    if (capRec > STAGE_CAP) capRec = STAGE_CAP;
    int capC = (capRec + BIN_SZ * 3 + 515) & ~3;             // csr capacity (pads), 4-aligned

    char* wsb = (char*)d_ws;
    size_t off = 0;
    int*      cursor  = (int*)(wsb + off);      off = align256(off + (size_t)nb * 4);
    int*      cursorG = (int*)(wsb + off);      off = align256(off + (size_t)N * 4);
    int2*     meta    = (int2*)(wsb + off);     off = align256(off + (size_t)N * 8);
    float*    dinv    = (float*)(wsb + off);    off = align256(off + (size_t)N * 4);
    __half*   gA0     = (__half*)(wsb + off);   off = align256(off + (size_t)(N + 1) * 32 * 2);
    __half*   gB0     = (__half*)(wsb + off);   off = align256(off + (size_t)(N + 1) * 8 * 2);
    __half*   gA1     = (__half*)(wsb + off);   off = align256(off + (size_t)(N + 1) * 32 * 2);
    __half*   gB1     = (__half*)(wsb + off);   off = align256(off + (size_t)(N + 1) * 8 * 2);
    unsigned* binned  = (unsigned*)(wsb + off); off = align256(off + (size_t)nb * capRec * 4);
    int*      csr     = (int*)(wsb + off);      off = align256(off + (size_t)nb * capC * 4);

    const int B = 256;
    const int nbGE = (N + 255) / 256;
    const unsigned GT = 5u * (unsigned)N;
    const int nbGA = (int)((GT + B - 1) / B);

    k_init  <<<(nb + 255) / 256, 256, 0, stream>>>(cursor, nb, capRec);
    kA3     <<<nchunk, B, 0, stream>>>(ei, E, nb, cursor, binned);
    kB      <<<nb, B, 0, stream>>>(binned, cursor, capRec, capC, meta, dinv, cursorG, csr, N);
    k_gemm  <<<nbGE, B, 0, stream>>>(x, W, dinv, gA0, gB0, N);
    k_gather<<<nbGA, B, 0, stream>>>(meta, csr, gA0, gB0, b, gA1, gB1, nullptr, N, 0);
    k_gather<<<nbGA, B, 0, stream>>>(meta, csr, gA1, gB1, b, nullptr, nullptr, out, N, 1);
}

// Round 12
// 213.432 us; speedup vs baseline: 1.0468x; 1.0468x over previous
//
#include <hip/hip_runtime.h>
#include <hip/hip_fp16.h>
#include <cstdint>

#define CDIM 40
#define FDIM 128
#define BIN_SHIFT 8      // 256 nodes per bin
#define BIN_SZ (1 << BIN_SHIFT)
#define CHUNK 4096       // edges per binning chunk
#define STAGE_CAP 8192   // LDS-staged csr ints per bin (32KB)

typedef _Float16 f16x8 __attribute__((ext_vector_type(8)));
typedef float f32x4 __attribute__((ext_vector_type(4)));

static __device__ __forceinline__ long long load_idx(const void* p, int is64, long long i) {
    if (is64) return ((const long long*)p)[i];
    return (long long)((const int*)p)[i];
}

static __device__ __forceinline__ unsigned packh2(float a, float b) {
    __half2 h;
    h.x = __float2half(a);
    h.y = __float2half(b);
    return *(unsigned*)&h;
}

// add 4 fp16 values (one uint2) into acc[0..4)
static __device__ __forceinline__ void addv2(float* acc, uint2 v) {
    const __half2* h = (const __half2*)&v;
    float2 f0 = __half22float2(h[0]);
    float2 f1 = __half22float2(h[1]);
    acc[0] += f0.x; acc[1] += f0.y; acc[2] += f1.x; acc[3] += f1.y;
}

static __device__ __forceinline__ f16x8 cvt8(float4 a, float4 b) {
    f16x8 r;
    r[0] = (_Float16)a.x; r[1] = (_Float16)a.y; r[2] = (_Float16)a.z; r[3] = (_Float16)a.w;
    r[4] = (_Float16)b.x; r[5] = (_Float16)b.y; r[6] = (_Float16)b.z; r[7] = (_Float16)b.w;
    return r;
}

// Init capacity cursors (tiny).
__global__ void k_init(int* cursor, int nb, int capRec) {
    int i = blockIdx.x * blockDim.x + threadIdx.x;
    if (i < nb) cursor[i] = i * capRec;
}

// Binning scatter into capacity-laid-out bins. Inline int64-vs-int32 detect
// (int64 LE values < 2^31 have all odd 32-bit words zero; impossible over
// ~2048 genuine int32 ids). Stage chunk in LDS, reserve per-bin ranges via
// global cursors, scatter 4B packed {dlocal:8 | src:17}. N <= 131072, nb <= 512.
__global__ __launch_bounds__(256) void kA3(const void* ei, long long E,
                                           int nb, int* __restrict__ cursor,
                                           unsigned* __restrict__ binned) {
    __shared__ unsigned lval[CHUNK];
    __shared__ unsigned short lbin[CHUNK];
    __shared__ int lcnt[512];
    __shared__ int lbase[512];
    __shared__ int lflag;
    int tid = threadIdx.x;
    if (tid == 0) lflag = 1;
    for (int i = tid; i < nb; i += 256) lcnt[i] = 0;
    __syncthreads();
    {
        const unsigned* w = (const unsigned*)ei;
        int nscan = (int)((2 * E < 4096) ? (2 * E) : 4096);
        for (int k = 1 + 2 * tid; k < nscan; k += 512)
            if (w[k] != 0u) lflag = 0;
    }
    __syncthreads();
    int is64 = lflag;
    long long base = (long long)blockIdx.x * CHUNK;
    int nk = (int)min((long long)CHUNK, E - base);
    for (int k = tid; k < nk; k += 256) {
        long long e = base + k;
        int s = (int)load_idx(ei, is64, e);
        int d = (int)load_idx(ei, is64, E + e);
        int bin = d >> BIN_SHIFT;
        lval[k] = (unsigned)s | ((unsigned)(d & (BIN_SZ - 1)) << 17);
        lbin[k] = (unsigned short)bin;
        atomicAdd(&lcnt[bin], 1);
    }
    __syncthreads();
    for (int i = tid; i < nb; i += 256) {
        int c = lcnt[i];
        lbase[i] = c ? atomicAdd(&cursor[i], c) : 0;
        lcnt[i] = 0;
    }
    __syncthreads();
    for (int k = tid; k < nk; k += 256) {
        int bin = lbin[k];
        int loc = atomicAdd(&lcnt[bin], 1);
        binned[lbase[bin] + loc] = lval[k];
    }
}

// Pass B: one block per bin (256 nodes). Per-node degree, dinv, packed
// permuted meta {rowp, node|deg<<17}, and the CSR segment: each node's list
// 4-aligned, padded with sentinel src=N (zero row). LDS build, int4 copy-out.
__global__ __launch_bounds__(256) void kB(const unsigned* __restrict__ binned,
                                          const int* __restrict__ cursor,
                                          int capRec, int capC,
                                          int2* __restrict__ meta,
                                          float* __restrict__ dinv,
                                          int* __restrict__ cursorG,
                                          int* __restrict__ csr, int N) {
    __shared__ int lcnt[BIN_SZ];
    __shared__ int lexcl[BIN_SZ];
    __shared__ int ls[256];
    __shared__ int dh[64];
    __shared__ int tot;
    __shared__ int stage[STAGE_CAP];
    int b = blockIdx.x, tid = threadIdx.x;
    int node0 = b << BIN_SHIFT;
    int nn = min(BIN_SZ, N - node0);
    int recBase = b * capRec;
    int csrBase = b * capC;
    int nedges = cursor[b] - recBase;

    lcnt[tid] = 0;
    if (tid < 64) dh[tid] = 0;
    __syncthreads();
    for (int t = tid; t < nedges; t += 256)
        atomicAdd(&lcnt[(binned[recBase + t] >> 17) & (BIN_SZ - 1)], 1);
    __syncthreads();
    int myc = lcnt[tid];
    int psz = (myc + 3) & ~3;          // padded size (4-aligned)
    ls[tid] = psz;
    __syncthreads();
    for (int off = 1; off < 256; off <<= 1) {
        int t = (tid >= off) ? ls[tid - off] : 0;
        __syncthreads();
        ls[tid] += t;
        __syncthreads();
    }
    int ex = ls[tid] - psz;            // 4-aligned start within bin
    lexcl[tid] = ex;
    if (tid == 255) tot = ls[255];
    if (tid < nn) {
        dinv[node0 + tid] = rsqrtf(1.0f + (float)myc);
        atomicAdd(&dh[min(myc, 63)], 1);
    }
    __syncthreads();
    int total = tot;                   // padded edge count of this bin
    // exclusive scan of 64 degree buckets
    int dv = (tid < 64) ? dh[tid] : 0;
    ls[tid] = dv;
    __syncthreads();
    for (int off = 1; off < 64; off <<= 1) {
        int t = (tid >= off) ? ls[tid - off] : 0;
        __syncthreads();
        ls[tid] += t;
        __syncthreads();
    }
    if (tid < 64) dh[tid] = ls[tid] - dv;
    __syncthreads();
    // degree-sorted permuted meta (ascending degree within bin)
    if (tid < nn) {
        int pos = atomicAdd(&dh[min(myc, 63)], 1);
        int2 mi;
        mi.x = csrBase + ex;
        mi.y = (node0 + tid) | (myc << 17);
        meta[node0 + pos] = mi;
    }
    __syncthreads();
    lcnt[tid] = ex;                    // cursors (real-entry region start)
    __syncthreads();
    if (total <= STAGE_CAP) {
        // prefill with sentinel N (covers pad slots)
        for (int t = tid; t < total; t += 256) stage[t] = N;
        __syncthreads();
        for (int t = tid; t < nedges; t += 256) {
            unsigned v = binned[recBase + t];
            int src = (int)(v & 0x1FFFFu);
            int dl  = (int)((v >> 17) & (BIN_SZ - 1));
            int p = atomicAdd(&lcnt[dl], 1);
            stage[p] = src;
        }
        __syncthreads();
        const int4* sp = (const int4*)stage;
        int4* cp = (int4*)(csr + csrBase);
        for (int t = tid; t < (total >> 2); t += 256) cp[t] = sp[t];
    } else {
        // overflow fallback (never hit for random graphs): global cursors
        if (tid < nn) cursorG[node0 + tid] = csrBase + ex;
        __syncthreads();
        for (int t = tid; t < nedges; t += 256) {
            unsigned v = binned[recBase + t];
            int src = (int)(v & 0x1FFFFu);
            int dl  = (int)((v >> 17) & (BIN_SZ - 1));
            int p = atomicAdd(&cursorG[node0 + dl], 1);
            csr[p] = src;
        }
        if (tid < nn)
            for (int k = myc; k < psz; ++k) csr[csrBase + ex + k] = N;
    }
}

// MFMA gemm: g[i,c] = fp16( dinv[i] * sum_f x[i,f]*W[c,f] ), split-store into
// gA[node][32ch] (64B rows) + gB[node][8ch] (16B rows). Wave = 16 nodes x 48ch
// (3 n-tiles, cols 40..47 zero-padded W). W lives in 12 register B-fragments.
// Also zeroes sentinel row N of gA/gB (pads in csr point at it).
__global__ __launch_bounds__(256) void k_gemm(const float* __restrict__ x,
                                              const float* __restrict__ W,
                                              const float* __restrict__ dinv,
                                              __half* __restrict__ gA,
                                              __half* __restrict__ gB, int N) {
    if (blockIdx.x == 0 && threadIdx.x < 20) {
        if (threadIdx.x < 16) ((unsigned*)(gA + (size_t)N * 32))[threadIdx.x] = 0u;
        else                  ((unsigned*)(gB + (size_t)N * 8))[threadIdx.x - 16] = 0u;
    }
    int wave = threadIdx.x >> 6;
    int lane = threadIdx.x & 63;
    int m = lane & 15;
    int quad = lane >> 4;
    f16x8 bfrag[3][4];
#pragma unroll
    for (int t = 0; t < 3; ++t) {
        int c = t * 16 + m;
#pragma unroll
        for (int q = 0; q < 4; ++q) {
            if (c < CDIM) {
                const float* wp = W + (size_t)c * FDIM + q * 32 + quad * 8;
                float4 w0 = *(const float4*)wp;
                float4 w1 = *(const float4*)(wp + 4);
                bfrag[t][q] = cvt8(w0, w1);
            } else {
                f16x8 z = {0, 0, 0, 0, 0, 0, 0, 0};
                bfrag[t][q] = z;
            }
        }
    }
#pragma unroll
    for (int i = 0; i < 4; ++i) {
        int nodebase = blockIdx.x * 256 + wave * 64 + i * 16;
        if (nodebase >= N) break;
        const float* xp = x + (size_t)(nodebase + m) * FDIM + quad * 8;
        f16x8 afrag[4];
#pragma unroll
        for (int q = 0; q < 4; ++q) {
            float4 x0 = *(const float4*)(xp + q * 32);
            float4 x1 = *(const float4*)(xp + q * 32 + 4);
            afrag[q] = cvt8(x0, x1);
        }
        f32x4 acc0 = {0, 0, 0, 0}, acc1 = {0, 0, 0, 0}, acc2 = {0, 0, 0, 0};
#pragma unroll
        for (int q = 0; q < 4; ++q) {
            acc0 = __builtin_amdgcn_mfma_f32_16x16x32_f16(afrag[q], bfrag[0][q], acc0, 0, 0, 0);
            acc1 = __builtin_amdgcn_mfma_f32_16x16x32_f16(afrag[q], bfrag[1][q], acc1, 0, 0, 0);
            acc2 = __builtin_amdgcn_mfma_f32_16x16x32_f16(afrag[q], bfrag[2][q], acc2, 0, 0, 0);
        }
        float4 dvv = *(const float4*)&dinv[nodebase + quad * 4];
        float ds[4] = {dvv.x, dvv.y, dvv.z, dvv.w};
#pragma unroll
        for (int r = 0; r < 4; ++r) {
            int node = nodebase + quad * 4 + r;
            gA[(size_t)node * 32 + m]      = __float2half(acc0[r] * ds[r]);
            gA[(size_t)node * 32 + 16 + m] = __float2half(acc1[r] * ds[r]);
            if (m < 8)
                gB[(size_t)node * 8 + m]   = __float2half(acc2[r] * ds[r]);
        }
    }
}

// One hop in g-space, split 10 ways per node: lane = (gidx, 4-ch chunk), 8B
// per edge per lane. c<8 read gA (64B rows; the 8 lanes of a node coalesce to
// one line), c=8,9 read gB (L2-resident). meta[gidx] (degree-sorted) packs
// {rowp, node|deg<<17}; csr read as int4 (4-aligned padded lists, pads ->
// zero row N). dinv recomputed from deg. 8-edge unroll for MLP.
// mode 0: write split fp16 (+ zero sentinel row); mode 1: fp32 out + bias.
__global__ __launch_bounds__(256) void k_gather(const int2* __restrict__ meta,
                                                const int* __restrict__ csr,
                                                const __half* __restrict__ gA,
                                                const __half* __restrict__ gB,
                                                const float* __restrict__ b,
                                                __half* __restrict__ goA,
                                                __half* __restrict__ goB,
                                                float* __restrict__ outF,
                                                int N, int mode) {
    unsigned t = blockIdx.x * 256 + threadIdx.x;
    if (mode == 0 && t < 20) {
        if (t < 16) ((unsigned*)(goA + (size_t)N * 32))[t] = 0u;
        else        ((unsigned*)(goB + (size_t)N * 8))[t - 16] = 0u;
    }
    unsigned gidx = t / 10, c = t - gidx * 10;
    if (gidx >= (unsigned)N) return;
    int2 mi = meta[gidx];
    int j = mi.x;
    int node = mi.y & 0x1FFFF;
    int deg = mi.y >> 17;
    int end_pad = j + ((deg + 3) & ~3);
    const uint2* src;
    unsigned stride;
    if (c < 8) { src = (const uint2*)gA + c;       stride = 8; }
    else       { src = (const uint2*)gB + (c - 8); stride = 2; }
    float acc[4] = {0.0f, 0.0f, 0.0f, 0.0f};
    addv2(acc, src[(size_t)node * stride]);
    for (; j + 8 <= end_pad; j += 8) {
        int4 c0 = *(const int4*)&csr[j];
        int4 c1 = *(const int4*)&csr[j + 4];
        uint2 v0 = src[(size_t)c0.x * stride];
        uint2 v1 = src[(size_t)c0.y * stride];
        uint2 v2 = src[(size_t)c0.z * stride];
        uint2 v3 = src[(size_t)c0.w * stride];
        uint2 v4 = src[(size_t)c1.x * stride];
        uint2 v5 = src[(size_t)c1.y * stride];
        uint2 v6 = src[(size_t)c1.z * stride];
        uint2 v7 = src[(size_t)c1.w * stride];
        addv2(acc, v0); addv2(acc, v1); addv2(acc, v2); addv2(acc, v3);
        addv2(acc, v4); addv2(acc, v5); addv2(acc, v6); addv2(acc, v7);
    }
    if (j < end_pad) {
        int4 c0 = *(const int4*)&csr[j];
        uint2 v0 = src[(size_t)c0.x * stride];
        uint2 v1 = src[(size_t)c0.y * stride];
        uint2 v2 = src[(size_t)c0.z * stride];
        uint2 v3 = src[(size_t)c0.w * stride];
        addv2(acc, v0); addv2(acc, v1); addv2(acc, v2); addv2(acc, v3);
    }
    float d = rsqrtf(1.0f + (float)deg);
    if (mode == 0) {
        float s = d * d;
        uint2 o;
        o.x = packh2(acc[0] * s, acc[1] * s);
        o.y = packh2(acc[2] * s, acc[3] * s);
        if (c < 8) ((uint2*)goA)[(size_t)node * 8 + c] = o;
        else       ((uint2*)goB)[(size_t)node * 2 + (c - 8)] = o;
    } else {
        float4 bv = ((const float4*)b)[c];
        float4 o;
        o.x = acc[0] * d + bv.x;
        o.y = acc[1] * d + bv.y;
        o.z = acc[2] * d + bv.z;
        o.w = acc[3] * d + bv.w;
        ((float4*)outF)[(size_t)node * 10 + c] = o;
    }
}

static inline size_t align256(size_t v) { return (v + 255) & ~(size_t)255; }

extern "C" void kernel_launch(void* const* d_in, const int* in_sizes, int n_in,
                              void* d_out, int out_size, void* d_ws, size_t ws_size,
                              hipStream_t stream) {
    const float* x  = (const float*)d_in[0];
    const void*  ei = d_in[1];
    const float* W  = (const float*)d_in[2];
    const float* b  = (const float*)d_in[3];
    float* out = (float*)d_out;

    const int N = in_sizes[0] / FDIM;                 // 100000
    const long long E = (long long)in_sizes[1] / 2;   // 1600000

    const int nb     = (N + BIN_SZ - 1) >> BIN_SHIFT;        // 391 bins
    const int nchunk = (int)((E + CHUNK - 1) / CHUNK);       // 391 chunks
    int capRec = (int)(E / nb) + 2048;                       // record capacity
    if (capRec > STAGE_CAP) capRec = STAGE_CAP;
    int capC = (capRec + BIN_SZ * 3 + 1027) & ~3;            // csr capacity (pads), 4-aligned

    char* wsb = (char*)d_ws;
    size_t off = 0;
    int*      cursor  = (int*)(wsb + off);      off = align256(off + (size_t)nb * 4);
    int*      cursorG = (int*)(wsb + off);      off = align256(off + (size_t)N * 4);
    int2*     meta    = (int2*)(wsb + off);     off = align256(off + (size_t)N * 8);
    float*    dinv    = (float*)(wsb + off);    off = align256(off + (size_t)N * 4);
    __half*   gA0     = (__half*)(wsb + off);   off = align256(off + (size_t)(N + 1) * 32 * 2);
    __half*   gB0     = (__half*)(wsb + off);   off = align256(off + (size_t)(N + 1) * 8 * 2);
    __half*   gA1     = (__half*)(wsb + off);   off = align256(off + (size_t)(N + 1) * 32 * 2);
    __half*   gB1     = (__half*)(wsb + off);   off = align256(off + (size_t)(N + 1) * 8 * 2);
    unsigned* binned  = (unsigned*)(wsb + off); off = align256(off + (size_t)nb * capRec * 4);
    int*      csr     = (int*)(wsb + off);      off = align256(off + (size_t)nb * capC * 4);

    const int B = 256;
    const int nbGE = (N + 255) / 256;
    const unsigned GT = 10u * (unsigned)N;
    const int nbGA = (int)((GT + B - 1) / B);

    k_init  <<<(nb + 255) / 256, 256, 0, stream>>>(cursor, nb, capRec);
    kA3     <<<nchunk, B, 0, stream>>>(ei, E, nb, cursor, binned);
    kB      <<<nb, B, 0, stream>>>(binned, cursor, capRec, capC, meta, dinv, cursorG, csr, N);
    k_gemm  <<<nbGE, B, 0, stream>>>(x, W, dinv, gA0, gB0, N);
    k_gather<<<nbGA, B, 0, stream>>>(meta, csr, gA0, gB0, b, gA1, gB1, nullptr, N, 0);
    k_gather<<<nbGA, B, 0, stream>>>(meta, csr, gA1, gB1, b, nullptr, nullptr, out, N, 1);
}